// Round 6
// baseline (339.655 us; speedup 1.0000x reference)
//
#include <hip/hip_runtime.h>
#include <math.h>

#define N_NODES 50000
#define IN_CH 256
#define HID_CH 128
#define OUT_CH 1000
#define TEXT_DIM 768
#define N_EDGES 800000
#define NBLK_SCAN 196   // ceil(50000/256)

typedef __attribute__((ext_vector_type(8))) short bf16x8;
typedef __attribute__((ext_vector_type(4))) float f32x4;

union U16B { uint4 u; bf16x8 b; ushort s[8]; };

__device__ inline ushort f2bf(float f) {
    union { float f; unsigned u; } v; v.f = f;
    unsigned u = v.u;
    unsigned r = (u + 0x7FFFu + ((u >> 16) & 1u)) >> 16;  // RNE
    return (ushort)r;
}
__device__ inline float bf2f(unsigned s) {
    union { unsigned u; float f; } v; v.u = s << 16; return v.f;
}

// ---------------------------------------------------------------------------
// Zero the pos/count buffer (50000 ints = 12500 int4) — replaces the
// pathologically slow graph-captured hipMemsetAsync blit (114us -> ~2us).
// ---------------------------------------------------------------------------
__global__ __launch_bounds__(256)
void k_zero(int4* __restrict__ p) {
    int i = blockIdx.x * 256 + threadIdx.x;
    if (i < N_NODES / 4) p[i] = make_int4(0, 0, 0, 0);
}

// ---------------------------------------------------------------------------
// CSR build
// ---------------------------------------------------------------------------
__global__ void k_count(const int* __restrict__ dst, int* __restrict__ pos, int e) {
    int i = blockIdx.x * blockDim.x + threadIdx.x;
    if (i < e) atomicAdd(&pos[dst[i]], 1);
}

// Phase A: per-block (256 counts) partial sums.
__global__ __launch_bounds__(256)
void k_blocksum(const int* __restrict__ cnt, int* __restrict__ partial, int n) {
    int i = blockIdx.x * 256 + threadIdx.x;
    int c = (i < n) ? cnt[i] : 0;
#pragma unroll
    for (int d = 32; d > 0; d >>= 1) c += __shfl_down(c, d);
    __shared__ int ws[4];
    if ((threadIdx.x & 63) == 0) ws[threadIdx.x >> 6] = c;
    __syncthreads();
    if (threadIdx.x == 0) partial[blockIdx.x] = ws[0] + ws[1] + ws[2] + ws[3];
}

// Phase B: one block scans the partials (exclusive), rowptr[N]=E.
__global__ __launch_bounds__(256)
void k_scan_partials(int* __restrict__ partial, int nb, int* __restrict__ rowptr) {
    int tid = threadIdx.x, lane = tid & 63, w = tid >> 6;
    if (tid == 0) rowptr[N_NODES] = N_EDGES;
    int c = (tid < nb) ? partial[tid] : 0;
    int x = c;
#pragma unroll
    for (int d = 1; d < 64; d <<= 1) { int t = __shfl_up(x, d); if (lane >= d) x += t; }
    __shared__ int ws[4];
    if (lane == 63) ws[w] = x;
    __syncthreads();
    if (tid == 0) { int r = 0; for (int k = 0; k < 4; ++k) { int t = ws[k]; ws[k] = r; r += t; } }
    __syncthreads();
    int excl = x - c + ws[w];
    if (tid < nb) partial[tid] = excl;
}

// Phase C: block-local scan + partial offset -> rowptr, pos cursor, dinv.
__global__ __launch_bounds__(256)
void k_scan_finish(int* __restrict__ cnt_pos, const int* __restrict__ ppref,
                   int* __restrict__ rowptr, float* __restrict__ dinv, int n) {
    int i = blockIdx.x * 256 + threadIdx.x;
    int lane = threadIdx.x & 63, w = threadIdx.x >> 6;
    int c = (i < n) ? cnt_pos[i] : 0;
    int x = c;
#pragma unroll
    for (int d = 1; d < 64; d <<= 1) { int t = __shfl_up(x, d); if (lane >= d) x += t; }
    __shared__ int ws[4];
    if (lane == 63) ws[w] = x;
    __syncthreads();
    if (threadIdx.x == 0) { int r = 0; for (int k = 0; k < 4; ++k) { int t = ws[k]; ws[k] = r; r += t; } }
    __syncthreads();
    int excl = x - c + ws[w] + ppref[blockIdx.x];
    if (i < n) {
        rowptr[i] = excl;
        cnt_pos[i] = excl;
        dinv[i] = rsqrtf(1.0f + (float)c);
    }
}

__global__ void k_fill(const int* __restrict__ src, const int* __restrict__ dst,
                       int* __restrict__ pos, const float* __restrict__ dinv,
                       int2* __restrict__ csr, int e) {
    int i = blockIdx.x * blockDim.x + threadIdx.x;
    if (i < e) {
        int s = src[i], d = dst[i];
        int slot = atomicAdd(&pos[d], 1);
        float nm = dinv[s] * dinv[d];
        csr[slot] = make_int2(s, __float_as_int(nm));
    }
}

// ---------------------------------------------------------------------------
// k_prep: fused weight transposes (fp32 [K][ld] -> bf16 [Npad][K]) + tvec.
// Blocks 0..7: Wt1, 8..11: Wt2, 12..43: Wct, 44..47: tvec (no atomics).
// ---------------------------------------------------------------------------
__device__ void transpose_tile(const float* __restrict__ in, int ld_in, int Ndim,
                               int Kdim, ushort* __restrict__ out, int bx, int by) {
    __shared__ float t[64][65];
    int n0 = bx * 64, k0 = by * 64;
    int c = threadIdx.x & 63, r0 = threadIdx.x >> 6;
    for (int r = r0; r < 64; r += 4) {
        int n = n0 + c, k = k0 + r;
        t[r][c] = (n < Ndim) ? in[(size_t)k * ld_in + n] : 0.f;
    }
    __syncthreads();
    for (int r = r0; r < 64; r += 4) {
        out[(size_t)(n0 + r) * Kdim + k0 + c] = f2bf(t[c][r]);
    }
}

__global__ __launch_bounds__(256)
void k_prep(const float* __restrict__ W1, const float* __restrict__ W2,
            const float* __restrict__ Wc, const float* __restrict__ bc,
            const float* __restrict__ text,
            ushort* __restrict__ Wt1, ushort* __restrict__ Wt2,
            ushort* __restrict__ Wct, float* __restrict__ tvec) {
    int b = blockIdx.x;
    if (b < 8) {                       // Wt1: [256][128] -> [128][256]
        transpose_tile(W1, HID_CH, HID_CH, IN_CH, Wt1, b % 2, b / 2);
    } else if (b < 12) {               // Wt2: [128][128] -> [128][128]
        int j = b - 8;
        transpose_tile(W2, HID_CH, HID_CH, HID_CH, Wt2, j % 2, j / 2);
    } else if (b < 44) {               // Wct: Wc[:128] [128][1000] -> [1024][128]
        int j = b - 12;
        transpose_tile(Wc, OUT_CH, OUT_CH, HID_CH, Wct, j % 16, j / 16);
    } else {                           // tvec: 4 o-chunks, full 768-sum each
        int o = (b - 44) * 256 + threadIdx.x;
        if (o < OUT_CH) {
            float acc = bc[o];
#pragma unroll 8
            for (int t = 0; t < TEXT_DIM; ++t)
                acc += text[t] * Wc[(size_t)(HID_CH + t) * OUT_CH + o];
            tvec[o] = acc;
        }
    }
}

// ---------------------------------------------------------------------------
// MFMA GEMM: C[M,N] = A[M,K] @ Bt[N,K]^T  (Bt pre-transposed bf16 [Npad][K])
// Block: 256 thr (2x2 waves), BM=64. NCH 64-col chunks at blockIdx.y*NCH.
// ---------------------------------------------------------------------------
template<int K, bool AF32, bool CLS, int NCH>
__global__ __launch_bounds__(256)
void k_mfma_gemm(const void* __restrict__ Av, const uint4* __restrict__ Bt,
                 void* __restrict__ Cv, const float* __restrict__ tvec,
                 int M, int N) {
    constexpr int SLOTS = K / 8;
    __shared__ uint4 ldsA[64 * SLOTS];
    __shared__ uint4 ldsB[64 * SLOTS];
    const int tid = threadIdx.x;
    const int lane = tid & 63;
    const int wid = tid >> 6;
    const int wm = wid >> 1, wn = wid & 1;
    const int mbase = blockIdx.x * 64;

    for (int i = tid; i < 64 * SLOTS; i += 256) {
        int row = i / SLOTS, slot = i % SLOTS;
        int grow = mbase + row;
        uint4 val = make_uint4(0u, 0u, 0u, 0u);
        if (grow < M) {
            if (AF32) {
                const float4* Af = (const float4*)Av;
                float4 f0 = Af[(size_t)grow * (K / 4) + slot * 2];
                float4 f1 = Af[(size_t)grow * (K / 4) + slot * 2 + 1];
                U16B o;
                o.s[0] = f2bf(f0.x); o.s[1] = f2bf(f0.y);
                o.s[2] = f2bf(f0.z); o.s[3] = f2bf(f0.w);
                o.s[4] = f2bf(f1.x); o.s[5] = f2bf(f1.y);
                o.s[6] = f2bf(f1.z); o.s[7] = f2bf(f1.w);
                val = o.u;
            } else {
                const uint4* Au = (const uint4*)Av;
                val = Au[(size_t)grow * SLOTS + slot];
            }
        }
        ldsA[row * SLOTS + (slot ^ (row & 7))] = val;
    }
    __syncthreads();

    bf16x8 afrag[2][K / 32];
#pragma unroll
    for (int mi = 0; mi < 2; ++mi) {
        int row = wm * 32 + mi * 16 + (lane & 15);
#pragma unroll
        for (int ks = 0; ks < K / 32; ++ks) {
            int slot = ks * 4 + (lane >> 4);
            U16B u; u.u = ldsA[row * SLOTS + (slot ^ (row & 7))];
            afrag[mi][ks] = u.b;
        }
    }

#pragma unroll
    for (int chi = 0; chi < NCH; ++chi) {
        int nbase = (blockIdx.y * NCH + chi) * 64;
        __syncthreads();
        for (int i = tid; i < 64 * SLOTS; i += 256) {
            int row = i / SLOTS, slot = i % SLOTS;
            ldsB[row * SLOTS + (slot ^ (row & 7))] = Bt[(size_t)(nbase + row) * SLOTS + slot];
        }
        __syncthreads();

        f32x4 acc[2][2];
#pragma unroll
        for (int mi = 0; mi < 2; ++mi)
#pragma unroll
            for (int ni = 0; ni < 2; ++ni)
                acc[mi][ni] = f32x4{0.f, 0.f, 0.f, 0.f};

#pragma unroll
        for (int ks = 0; ks < K / 32; ++ks) {
            bf16x8 bfr[2];
#pragma unroll
            for (int ni = 0; ni < 2; ++ni) {
                int row = wn * 32 + ni * 16 + (lane & 15);
                int slot = ks * 4 + (lane >> 4);
                U16B u; u.u = ldsB[row * SLOTS + (slot ^ (row & 7))];
                bfr[ni] = u.b;
            }
#pragma unroll
            for (int mi = 0; mi < 2; ++mi)
#pragma unroll
                for (int ni = 0; ni < 2; ++ni)
                    acc[mi][ni] = __builtin_amdgcn_mfma_f32_16x16x32_bf16(
                        afrag[mi][ks], bfr[ni], acc[mi][ni], 0, 0, 0);
        }

#pragma unroll
        for (int ni = 0; ni < 2; ++ni) {
            int col = nbase + wn * 32 + ni * 16 + (lane & 15);
            float tv = 0.f;
            if (CLS) tv = (col < N) ? tvec[col] : 0.f;
#pragma unroll
            for (int mi = 0; mi < 2; ++mi) {
                int r0 = mbase + wm * 32 + mi * 16 + (lane >> 4) * 4;
#pragma unroll
                for (int j = 0; j < 4; ++j) {
                    int r = r0 + j;
                    if (CLS) {
                        if (r < M && col < N)
                            ((float*)Cv)[(size_t)r * N + col] = acc[mi][ni][j] + tv;
                    } else {
                        if (r < M)
                            ((ushort*)Cv)[(size_t)r * N + col] = f2bf(acc[mi][ni][j]);
                    }
                }
            }
        }
    }
}

// ---------------------------------------------------------------------------
// Aggregate (bf16 H): one wave per node, lane = 2 channels (bf16x2 u32).
// csr entries are int2 {src, norm_bits}; unroll-4 batched gathers.
// ---------------------------------------------------------------------------
template<bool RELU>
__global__ __launch_bounds__(256)
void k_agg(const unsigned* __restrict__ Hu, const int* __restrict__ rowptr,
           const int2* __restrict__ csr, const float* __restrict__ dinv,
           const float* __restrict__ bias, unsigned* __restrict__ Ou) {
    int v = blockIdx.x * 4 + (threadIdx.x >> 6);
    if (v >= N_NODES) return;
    int lane = threadIdx.x & 63;
    float di = dinv[v];
    float sw = di * di;
    unsigned h = Hu[(size_t)v * 64 + lane];
    float a0 = bf2f(h & 0xffffu) * sw + bias[lane * 2];
    float a1 = bf2f(h >> 16) * sw + bias[lane * 2 + 1];
    int e = rowptr[v], e1 = rowptr[v + 1];
    for (; e + 4 <= e1; e += 4) {
        int2 c0 = csr[e],     c1 = csr[e + 1];
        int2 c2 = csr[e + 2], c3 = csr[e + 3];
        float w0 = __int_as_float(c0.y), w1 = __int_as_float(c1.y);
        float w2 = __int_as_float(c2.y), w3 = __int_as_float(c3.y);
        unsigned q0 = Hu[(size_t)c0.x * 64 + lane];
        unsigned q1 = Hu[(size_t)c1.x * 64 + lane];
        unsigned q2 = Hu[(size_t)c2.x * 64 + lane];
        unsigned q3 = Hu[(size_t)c3.x * 64 + lane];
        a0 += bf2f(q0 & 0xffffu) * w0 + bf2f(q1 & 0xffffu) * w1
            + bf2f(q2 & 0xffffu) * w2 + bf2f(q3 & 0xffffu) * w3;
        a1 += bf2f(q0 >> 16) * w0 + bf2f(q1 >> 16) * w1
            + bf2f(q2 >> 16) * w2 + bf2f(q3 >> 16) * w3;
    }
    for (; e < e1; ++e) {
        int2 ce = csr[e];
        float w = __int_as_float(ce.y);
        unsigned q = Hu[(size_t)ce.x * 64 + lane];
        a0 += bf2f(q & 0xffffu) * w;
        a1 += bf2f(q >> 16) * w;
    }
    if (RELU) { a0 = fmaxf(a0, 0.f); a1 = fmaxf(a1, 0.f); }
    Ou[(size_t)v * 64 + lane] = (unsigned)f2bf(a0) | ((unsigned)f2bf(a1) << 16);
}

// ---------------------------------------------------------------------------
extern "C" void kernel_launch(void* const* d_in, const int* in_sizes, int n_in,
                              void* d_out, int out_size, void* d_ws, size_t ws_size,
                              hipStream_t stream) {
    const float* x    = (const float*)d_in[0];
    const int*   ei   = (const int*)d_in[1];
    const float* text = (const float*)d_in[2];
    const float* W1   = (const float*)d_in[3];
    const float* b1   = (const float*)d_in[4];
    const float* W2   = (const float*)d_in[5];
    const float* b2   = (const float*)d_in[6];
    const float* Wc   = (const float*)d_in[7];
    const float* bc   = (const float*)d_in[8];
    float* out = (float*)d_out;

    const int* e_src = ei;
    const int* e_dst = ei + N_EDGES;

    char* ws = (char*)d_ws;
    size_t off = 0;
    auto alloc = [&](size_t bytes) {
        size_t o = off;
        off += (bytes + 255) & ~(size_t)255;
        return o;
    };
    ushort* h0      = (ushort*)(ws + alloc((size_t)N_NODES * HID_CH * 2));
    ushort* h1      = (ushort*)(ws + alloc((size_t)N_NODES * HID_CH * 2));
    float*  dinv    = (float*) (ws + alloc((size_t)N_NODES * 4));
    int*    rowptr  = (int*)   (ws + alloc((size_t)(N_NODES + 1) * 4));
    int*    pos     = (int*)   (ws + alloc((size_t)N_NODES * 4));
    int*    partial = (int*)   (ws + alloc((size_t)NBLK_SCAN * 4));
    int2*   csr     = (int2*)  (ws + alloc((size_t)N_EDGES * 8));
    float*  tvec    = (float*) (ws + alloc((size_t)OUT_CH * 4));
    ushort* Wt1     = (ushort*)(ws + alloc((size_t)HID_CH * IN_CH * 2));
    ushort* Wt2     = (ushort*)(ws + alloc((size_t)HID_CH * HID_CH * 2));
    ushort* Wct     = (ushort*)(ws + alloc((size_t)1024 * HID_CH * 2));
    (void)ws_size; (void)in_sizes; (void)n_in; (void)out_size;

    // --- graph structure ---
    k_zero<<<(N_NODES / 4 + 255) / 256, 256, 0, stream>>>((int4*)pos);
    k_count<<<(N_EDGES + 255) / 256, 256, 0, stream>>>(e_dst, pos, N_EDGES);
    k_blocksum<<<NBLK_SCAN, 256, 0, stream>>>(pos, partial, N_NODES);
    k_scan_partials<<<1, 256, 0, stream>>>(partial, NBLK_SCAN, rowptr);
    k_scan_finish<<<NBLK_SCAN, 256, 0, stream>>>(pos, partial, rowptr, dinv, N_NODES);
    k_fill<<<(N_EDGES + 255) / 256, 256, 0, stream>>>(e_src, e_dst, pos, dinv,
                                                      csr, N_EDGES);

    // --- fused prep: weight transposes + tvec (no atomics) ---
    k_prep<<<48, 256, 0, stream>>>(W1, W2, Wc, bc, text, Wt1, Wt2, Wct, tvec);

    const int mtiles = (N_NODES + 63) / 64;   // 782

    // --- layer 1: x @ W1 (fp32 A, K=256) -> h0 bf16 ---
    k_mfma_gemm<IN_CH, true, false, 2><<<dim3(mtiles, 1), 256, 0, stream>>>(
        x, (const uint4*)Wt1, h0, nullptr, N_NODES, HID_CH);
    k_agg<true><<<(N_NODES + 3) / 4, 256, 0, stream>>>(
        (const unsigned*)h0, rowptr, csr, dinv, b1, (unsigned*)h1);

    // --- layer 2: h1 @ W2 (bf16 A, K=128) -> h0 bf16 ---
    k_mfma_gemm<HID_CH, false, false, 2><<<dim3(mtiles, 1), 256, 0, stream>>>(
        h1, (const uint4*)Wt2, h0, nullptr, N_NODES, HID_CH);
    k_agg<false><<<(N_NODES + 3) / 4, 256, 0, stream>>>(
        (const unsigned*)h0, rowptr, csr, dinv, b2, (unsigned*)h1);

    // --- classifier: h1 @ Wct^T + tvec -> out fp32, N-chunks split on grid.y ---
    k_mfma_gemm<HID_CH, false, true, 4><<<dim3(mtiles, 4), 256, 0, stream>>>(
        h1, (const uint4*)Wct, out, tvec, N_NODES, OUT_CH);
}

// Round 7
// 292.499 us; speedup vs baseline: 1.1612x; 1.1612x over previous
//
#include <hip/hip_runtime.h>
#include <math.h>

#define N_NODES 50000
#define IN_CH 256
#define HID_CH 128
#define OUT_CH 1000
#define TEXT_DIM 768
#define N_EDGES 800000
#define NBLK_SCAN 196   // ceil(50000/256)

typedef __attribute__((ext_vector_type(8))) short bf16x8;
typedef __attribute__((ext_vector_type(4))) float f32x4;

union U16B { uint4 u; bf16x8 b; ushort s[8]; };

__device__ inline ushort f2bf(float f) {
    union { float f; unsigned u; } v; v.f = f;
    unsigned u = v.u;
    unsigned r = (u + 0x7FFFu + ((u >> 16) & 1u)) >> 16;  // RNE
    return (ushort)r;
}
__device__ inline float bf2f(unsigned s) {
    union { unsigned u; float f; } v; v.u = s << 16; return v.f;
}

// ---------------------------------------------------------------------------
// Zero pos (50000 ints) and tvec (1000 floats). Replaces slow memset blit.
// ---------------------------------------------------------------------------
__global__ __launch_bounds__(256)
void k_zero(int4* __restrict__ pos4, float4* __restrict__ tvec4) {
    int i = blockIdx.x * 256 + threadIdx.x;
    if (i < N_NODES / 4) pos4[i] = make_int4(0, 0, 0, 0);
    if (i < OUT_CH / 4) tvec4[i] = make_float4(0.f, 0.f, 0.f, 0.f);
}

// ---------------------------------------------------------------------------
// CSR build
// ---------------------------------------------------------------------------
__global__ void k_count(const int* __restrict__ dst, int* __restrict__ pos, int e) {
    int i = blockIdx.x * blockDim.x + threadIdx.x;
    if (i < e) atomicAdd(&pos[dst[i]], 1);
}

// Phase A: per-block (256 counts) partial sums.
__global__ __launch_bounds__(256)
void k_blocksum(const int* __restrict__ cnt, int* __restrict__ partial, int n) {
    int i = blockIdx.x * 256 + threadIdx.x;
    int c = (i < n) ? cnt[i] : 0;
#pragma unroll
    for (int d = 32; d > 0; d >>= 1) c += __shfl_down(c, d);
    __shared__ int ws[4];
    if ((threadIdx.x & 63) == 0) ws[threadIdx.x >> 6] = c;
    __syncthreads();
    if (threadIdx.x == 0) partial[blockIdx.x] = ws[0] + ws[1] + ws[2] + ws[3];
}

// Phase B: one block scans the partials (exclusive), rowptr[N]=E.
__global__ __launch_bounds__(256)
void k_scan_partials(int* __restrict__ partial, int nb, int* __restrict__ rowptr) {
    int tid = threadIdx.x, lane = tid & 63, w = tid >> 6;
    if (tid == 0) rowptr[N_NODES] = N_EDGES;
    int c = (tid < nb) ? partial[tid] : 0;
    int x = c;
#pragma unroll
    for (int d = 1; d < 64; d <<= 1) { int t = __shfl_up(x, d); if (lane >= d) x += t; }
    __shared__ int ws[4];
    if (lane == 63) ws[w] = x;
    __syncthreads();
    if (tid == 0) { int r = 0; for (int k = 0; k < 4; ++k) { int t = ws[k]; ws[k] = r; r += t; } }
    __syncthreads();
    int excl = x - c + ws[w];
    if (tid < nb) partial[tid] = excl;
}

// Phase C: block-local scan + partial offset -> rowptr, pos cursor, dinv.
__global__ __launch_bounds__(256)
void k_scan_finish(int* __restrict__ cnt_pos, const int* __restrict__ ppref,
                   int* __restrict__ rowptr, float* __restrict__ dinv, int n) {
    int i = blockIdx.x * 256 + threadIdx.x;
    int lane = threadIdx.x & 63, w = threadIdx.x >> 6;
    int c = (i < n) ? cnt_pos[i] : 0;
    int x = c;
#pragma unroll
    for (int d = 1; d < 64; d <<= 1) { int t = __shfl_up(x, d); if (lane >= d) x += t; }
    __shared__ int ws[4];
    if (lane == 63) ws[w] = x;
    __syncthreads();
    if (threadIdx.x == 0) { int r = 0; for (int k = 0; k < 4; ++k) { int t = ws[k]; ws[k] = r; r += t; } }
    __syncthreads();
    int excl = x - c + ws[w] + ppref[blockIdx.x];
    if (i < n) {
        rowptr[i] = excl;
        cnt_pos[i] = excl;
        dinv[i] = rsqrtf(1.0f + (float)c);
    }
}

__global__ void k_fill(const int* __restrict__ src, const int* __restrict__ dst,
                       int* __restrict__ pos, const float* __restrict__ dinv,
                       int2* __restrict__ csr, int e) {
    int i = blockIdx.x * blockDim.x + threadIdx.x;
    if (i < e) {
        int s = src[i], d = dst[i];
        int slot = atomicAdd(&pos[d], 1);
        float nm = dinv[s] * dinv[d];
        csr[slot] = make_int2(s, __float_as_int(nm));
    }
}

// ---------------------------------------------------------------------------
// k_prep: fused weight transposes (fp32 [K][ld] -> bf16 [Npad][K]) + tvec.
// Blocks 0..7: Wt1, 8..11: Wt2, 12..43: Wct, 44..91: tvec chunks (atomic).
// tvec pre-zeroed by k_zero; bc folded into chunk t0==0.
// ---------------------------------------------------------------------------
__device__ void transpose_tile(const float* __restrict__ in, int ld_in, int Ndim,
                               int Kdim, ushort* __restrict__ out, int bx, int by) {
    __shared__ float t[64][65];
    int n0 = bx * 64, k0 = by * 64;
    int c = threadIdx.x & 63, r0 = threadIdx.x >> 6;
    for (int r = r0; r < 64; r += 4) {
        int n = n0 + c, k = k0 + r;
        t[r][c] = (n < Ndim) ? in[(size_t)k * ld_in + n] : 0.f;
    }
    __syncthreads();
    for (int r = r0; r < 64; r += 4) {
        out[(size_t)(n0 + r) * Kdim + k0 + c] = f2bf(t[c][r]);
    }
}

__global__ __launch_bounds__(256)
void k_prep(const float* __restrict__ W1, const float* __restrict__ W2,
            const float* __restrict__ Wc, const float* __restrict__ bc,
            const float* __restrict__ text,
            ushort* __restrict__ Wt1, ushort* __restrict__ Wt2,
            ushort* __restrict__ Wct, float* __restrict__ tvec) {
    int b = blockIdx.x;
    if (b < 8) {                       // Wt1: [256][128] -> [128][256]
        transpose_tile(W1, HID_CH, HID_CH, IN_CH, Wt1, b % 2, b / 2);
    } else if (b < 12) {               // Wt2: [128][128] -> [128][128]
        int j = b - 8;
        transpose_tile(W2, HID_CH, HID_CH, HID_CH, Wt2, j % 2, j / 2);
    } else if (b < 44) {               // Wct: Wc[:128] [128][1000] -> [1024][128]
        int j = b - 12;
        transpose_tile(Wc, OUT_CH, OUT_CH, HID_CH, Wct, j % 16, j / 16);
    } else {                           // tvec: 4 o-chunks x 12 t-chunks, atomic
        int j = b - 44;
        int o = (j & 3) * 256 + threadIdx.x;
        int t0 = (j >> 2) * 64;
        if (o < OUT_CH) {
            float acc = (t0 == 0) ? bc[o] : 0.f;
#pragma unroll 4
            for (int t = t0; t < t0 + 64; ++t)
                acc += text[t] * Wc[(size_t)(HID_CH + t) * OUT_CH + o];
            atomicAdd(&tvec[o], acc);
        }
    }
}

// ---------------------------------------------------------------------------
// MFMA GEMM: C[M,N] = A[M,K] @ Bt[N,K]^T  (Bt pre-transposed bf16 [Npad][K])
// Block: 256 thr (2x2 waves), BM=64. NCH 64-col chunks at blockIdx.y*NCH.
// ---------------------------------------------------------------------------
template<int K, bool AF32, bool CLS, int NCH>
__global__ __launch_bounds__(256)
void k_mfma_gemm(const void* __restrict__ Av, const uint4* __restrict__ Bt,
                 void* __restrict__ Cv, const float* __restrict__ tvec,
                 int M, int N) {
    constexpr int SLOTS = K / 8;
    __shared__ uint4 ldsA[64 * SLOTS];
    __shared__ uint4 ldsB[64 * SLOTS];
    const int tid = threadIdx.x;
    const int lane = tid & 63;
    const int wid = tid >> 6;
    const int wm = wid >> 1, wn = wid & 1;
    const int mbase = blockIdx.x * 64;

    for (int i = tid; i < 64 * SLOTS; i += 256) {
        int row = i / SLOTS, slot = i % SLOTS;
        int grow = mbase + row;
        uint4 val = make_uint4(0u, 0u, 0u, 0u);
        if (grow < M) {
            if (AF32) {
                const float4* Af = (const float4*)Av;
                float4 f0 = Af[(size_t)grow * (K / 4) + slot * 2];
                float4 f1 = Af[(size_t)grow * (K / 4) + slot * 2 + 1];
                U16B o;
                o.s[0] = f2bf(f0.x); o.s[1] = f2bf(f0.y);
                o.s[2] = f2bf(f0.z); o.s[3] = f2bf(f0.w);
                o.s[4] = f2bf(f1.x); o.s[5] = f2bf(f1.y);
                o.s[6] = f2bf(f1.z); o.s[7] = f2bf(f1.w);
                val = o.u;
            } else {
                const uint4* Au = (const uint4*)Av;
                val = Au[(size_t)grow * SLOTS + slot];
            }
        }
        ldsA[row * SLOTS + (slot ^ (row & 7))] = val;
    }
    __syncthreads();

    bf16x8 afrag[2][K / 32];
#pragma unroll
    for (int mi = 0; mi < 2; ++mi) {
        int row = wm * 32 + mi * 16 + (lane & 15);
#pragma unroll
        for (int ks = 0; ks < K / 32; ++ks) {
            int slot = ks * 4 + (lane >> 4);
            U16B u; u.u = ldsA[row * SLOTS + (slot ^ (row & 7))];
            afrag[mi][ks] = u.b;
        }
    }

#pragma unroll
    for (int chi = 0; chi < NCH; ++chi) {
        int nbase = (blockIdx.y * NCH + chi) * 64;
        __syncthreads();
        for (int i = tid; i < 64 * SLOTS; i += 256) {
            int row = i / SLOTS, slot = i % SLOTS;
            ldsB[row * SLOTS + (slot ^ (row & 7))] = Bt[(size_t)(nbase + row) * SLOTS + slot];
        }
        __syncthreads();

        f32x4 acc[2][2];
#pragma unroll
        for (int mi = 0; mi < 2; ++mi)
#pragma unroll
            for (int ni = 0; ni < 2; ++ni)
                acc[mi][ni] = f32x4{0.f, 0.f, 0.f, 0.f};

#pragma unroll
        for (int ks = 0; ks < K / 32; ++ks) {
            bf16x8 bfr[2];
#pragma unroll
            for (int ni = 0; ni < 2; ++ni) {
                int row = wn * 32 + ni * 16 + (lane & 15);
                int slot = ks * 4 + (lane >> 4);
                U16B u; u.u = ldsB[row * SLOTS + (slot ^ (row & 7))];
                bfr[ni] = u.b;
            }
#pragma unroll
            for (int mi = 0; mi < 2; ++mi)
#pragma unroll
                for (int ni = 0; ni < 2; ++ni)
                    acc[mi][ni] = __builtin_amdgcn_mfma_f32_16x16x32_bf16(
                        afrag[mi][ks], bfr[ni], acc[mi][ni], 0, 0, 0);
        }

#pragma unroll
        for (int ni = 0; ni < 2; ++ni) {
            int col = nbase + wn * 32 + ni * 16 + (lane & 15);
            float tv = 0.f;
            if (CLS) tv = (col < N) ? tvec[col] : 0.f;
#pragma unroll
            for (int mi = 0; mi < 2; ++mi) {
                int r0 = mbase + wm * 32 + mi * 16 + (lane >> 4) * 4;
#pragma unroll
                for (int j = 0; j < 4; ++j) {
                    int r = r0 + j;
                    if (CLS) {
                        if (r < M && col < N)
                            ((float*)Cv)[(size_t)r * N + col] = acc[mi][ni][j] + tv;
                    } else {
                        if (r < M)
                            ((ushort*)Cv)[(size_t)r * N + col] = f2bf(acc[mi][ni][j]);
                    }
                }
            }
        }
    }
}

// ---------------------------------------------------------------------------
// Aggregate (bf16 H): one wave per node, lane = 2 channels (bf16x2 u32).
// ---------------------------------------------------------------------------
template<bool RELU>
__global__ __launch_bounds__(256)
void k_agg(const unsigned* __restrict__ Hu, const int* __restrict__ rowptr,
           const int2* __restrict__ csr, const float* __restrict__ dinv,
           const float* __restrict__ bias, unsigned* __restrict__ Ou) {
    int v = blockIdx.x * 4 + (threadIdx.x >> 6);
    if (v >= N_NODES) return;
    int lane = threadIdx.x & 63;
    float di = dinv[v];
    float sw = di * di;
    unsigned h = Hu[(size_t)v * 64 + lane];
    float a0 = bf2f(h & 0xffffu) * sw + bias[lane * 2];
    float a1 = bf2f(h >> 16) * sw + bias[lane * 2 + 1];
    int e = rowptr[v], e1 = rowptr[v + 1];
    for (; e + 4 <= e1; e += 4) {
        int2 c0 = csr[e],     c1 = csr[e + 1];
        int2 c2 = csr[e + 2], c3 = csr[e + 3];
        float w0 = __int_as_float(c0.y), w1 = __int_as_float(c1.y);
        float w2 = __int_as_float(c2.y), w3 = __int_as_float(c3.y);
        unsigned q0 = Hu[(size_t)c0.x * 64 + lane];
        unsigned q1 = Hu[(size_t)c1.x * 64 + lane];
        unsigned q2 = Hu[(size_t)c2.x * 64 + lane];
        unsigned q3 = Hu[(size_t)c3.x * 64 + lane];
        a0 += bf2f(q0 & 0xffffu) * w0 + bf2f(q1 & 0xffffu) * w1
            + bf2f(q2 & 0xffffu) * w2 + bf2f(q3 & 0xffffu) * w3;
        a1 += bf2f(q0 >> 16) * w0 + bf2f(q1 >> 16) * w1
            + bf2f(q2 >> 16) * w2 + bf2f(q3 >> 16) * w3;
    }
    for (; e < e1; ++e) {
        int2 ce = csr[e];
        float w = __int_as_float(ce.y);
        unsigned q = Hu[(size_t)ce.x * 64 + lane];
        a0 += bf2f(q & 0xffffu) * w;
        a1 += bf2f(q >> 16) * w;
    }
    if (RELU) { a0 = fmaxf(a0, 0.f); a1 = fmaxf(a1, 0.f); }
    Ou[(size_t)v * 64 + lane] = (unsigned)f2bf(a0) | ((unsigned)f2bf(a1) << 16);
}

// ---------------------------------------------------------------------------
extern "C" void kernel_launch(void* const* d_in, const int* in_sizes, int n_in,
                              void* d_out, int out_size, void* d_ws, size_t ws_size,
                              hipStream_t stream) {
    const float* x    = (const float*)d_in[0];
    const int*   ei   = (const int*)d_in[1];
    const float* text = (const float*)d_in[2];
    const float* W1   = (const float*)d_in[3];
    const float* b1   = (const float*)d_in[4];
    const float* W2   = (const float*)d_in[5];
    const float* b2   = (const float*)d_in[6];
    const float* Wc   = (const float*)d_in[7];
    const float* bc   = (const float*)d_in[8];
    float* out = (float*)d_out;

    const int* e_src = ei;
    const int* e_dst = ei + N_EDGES;

    char* ws = (char*)d_ws;
    size_t off = 0;
    auto alloc = [&](size_t bytes) {
        size_t o = off;
        off += (bytes + 255) & ~(size_t)255;
        return o;
    };
    ushort* h0      = (ushort*)(ws + alloc((size_t)N_NODES * HID_CH * 2));
    ushort* h1      = (ushort*)(ws + alloc((size_t)N_NODES * HID_CH * 2));
    float*  dinv    = (float*) (ws + alloc((size_t)N_NODES * 4));
    int*    rowptr  = (int*)   (ws + alloc((size_t)(N_NODES + 1) * 4));
    int*    pos     = (int*)   (ws + alloc((size_t)N_NODES * 4));
    int*    partial = (int*)   (ws + alloc((size_t)NBLK_SCAN * 4));
    int2*   csr     = (int2*)  (ws + alloc((size_t)N_EDGES * 8));
    float*  tvec    = (float*) (ws + alloc((size_t)OUT_CH * 4));
    ushort* Wt1     = (ushort*)(ws + alloc((size_t)HID_CH * IN_CH * 2));
    ushort* Wt2     = (ushort*)(ws + alloc((size_t)HID_CH * HID_CH * 2));
    ushort* Wct     = (ushort*)(ws + alloc((size_t)1024 * HID_CH * 2));
    (void)ws_size; (void)in_sizes; (void)n_in; (void)out_size;

    // --- zero pos + tvec, then graph structure ---
    k_zero<<<(N_NODES / 4 + 255) / 256, 256, 0, stream>>>((int4*)pos, (float4*)tvec);
    k_count<<<(N_EDGES + 255) / 256, 256, 0, stream>>>(e_dst, pos, N_EDGES);
    k_blocksum<<<NBLK_SCAN, 256, 0, stream>>>(pos, partial, N_NODES);
    k_scan_partials<<<1, 256, 0, stream>>>(partial, NBLK_SCAN, rowptr);
    k_scan_finish<<<NBLK_SCAN, 256, 0, stream>>>(pos, partial, rowptr, dinv, N_NODES);
    k_fill<<<(N_EDGES + 255) / 256, 256, 0, stream>>>(e_src, e_dst, pos, dinv,
                                                      csr, N_EDGES);

    // --- fused prep: weight transposes + tvec (chunked atomic) ---
    k_prep<<<92, 256, 0, stream>>>(W1, W2, Wc, bc, text, Wt1, Wt2, Wct, tvec);

    const int mtiles = (N_NODES + 63) / 64;   // 782

    // --- layer 1: x @ W1 (fp32 A, K=256) -> h0 bf16 ---
    k_mfma_gemm<IN_CH, true, false, 2><<<dim3(mtiles, 1), 256, 0, stream>>>(
        x, (const uint4*)Wt1, h0, nullptr, N_NODES, HID_CH);
    k_agg<true><<<(N_NODES + 3) / 4, 256, 0, stream>>>(
        (const unsigned*)h0, rowptr, csr, dinv, b1, (unsigned*)h1);

    // --- layer 2: h1 @ W2 (bf16 A, K=128) -> h0 bf16 ---
    k_mfma_gemm<HID_CH, false, false, 2><<<dim3(mtiles, 1), 256, 0, stream>>>(
        h1, (const uint4*)Wt2, h0, nullptr, N_NODES, HID_CH);
    k_agg<false><<<(N_NODES + 3) / 4, 256, 0, stream>>>(
        (const unsigned*)h0, rowptr, csr, dinv, b2, (unsigned*)h1);

    // --- classifier: h1 @ Wct^T + tvec -> out fp32, N-chunks split on grid.y ---
    k_mfma_gemm<HID_CH, false, true, 4><<<dim3(mtiles, 4), 256, 0, stream>>>(
        h1, (const uint4*)Wct, out, tvec, N_NODES, OUT_CH);
}